// Round 8
// baseline (1734.080 us; speedup 1.0000x reference)
//
#include <hip/hip_runtime.h>
#include <math.h>

// ============================================================================
// CapsNet forward, round 8 (= round 7 resubmit; infra timeout, never ran).
//   conv2m v4: BM=BN=128, BK=32, wave tile 64x64 (LDS instr/step 144->96,
//     the measured LDS-pipe bound), split-K x2, reg-staged depth-1 prefetch.
//   k_route v2: W slice in LDS (40 KB), 64 batches per block -> W re-read
//     drops 3 GB -> 46 MB per pass.
//   Numerics: same fp16 hi/lo 3-pass MFMA; routing identical math.
//
// Workspace (bytes):
//   ahi [0, 104857600)            alo [104857600, 209715200)
//   whi [209715200, 220332032)    wlo [220332032, 230948864)
//   caps[230948864, 249823232)    (= p, squashed in place)
//   -- after conv2m, staging region dead; alias at 0:
//   spart [0, 47185920)  vsum [47185920, +327680)  vbuf [47513600, +327680)
//   din [47841280, +327680)  h1 [48168960, +1048576)  h2 [49217536, +2097152)
//   total ws use: 249,823,232 bytes (same as rounds 4-6)
// ============================================================================

typedef _Float16 f16x8 __attribute__((ext_vector_type(8)));
typedef float f32x4 __attribute__((ext_vector_type(4)));

// ---------------- conv1: x[512,1,28,28] -> relu -> ahi/alo[b][20][20][256] (x16)
__global__ __launch_bounds__(256) void k_conv1(const float* __restrict__ x,
        const float* __restrict__ w, const float* __restrict__ bias,
        _Float16* __restrict__ ahi, _Float16* __restrict__ alo) {
    __shared__ __align__(16) float xs[784];
    const int b = blockIdx.x;
    const int oy0 = blockIdx.y * 4;
    const int t = threadIdx.x;                     // = output channel ci
    for (int i = t; i < 784; i += 256) xs[i] = x[b * 784 + i];
    __syncthreads();

    float wr[81];
#pragma unroll
    for (int i = 0; i < 81; ++i) wr[i] = w[t * 81 + i];
    const float bv = bias[t];

    for (int oy = oy0; oy < oy0 + 4; ++oy) {
        float acc[20];
#pragma unroll
        for (int px = 0; px < 20; ++px) acc[px] = bv;
#pragma unroll
        for (int ky = 0; ky < 9; ++ky) {
            const float* xrow = &xs[(oy + ky) * 28];
            float xr[28];
#pragma unroll
            for (int j = 0; j < 7; ++j) {
                float4 v4 = *(const float4*)(xrow + j * 4);
                xr[j * 4 + 0] = v4.x; xr[j * 4 + 1] = v4.y;
                xr[j * 4 + 2] = v4.z; xr[j * 4 + 3] = v4.w;
            }
#pragma unroll
            for (int kx = 0; kx < 9; ++kx) {
                const float wv = wr[ky * 9 + kx];
#pragma unroll
                for (int px = 0; px < 20; ++px)
                    acc[px] = fmaf(wv, xr[px + kx], acc[px]);
            }
        }
#pragma unroll
        for (int px = 0; px < 20; ++px) {
            const float v16 = fmaxf(acc[px], 0.f) * 16.f;
            const _Float16 hi = (_Float16)v16;
            const _Float16 lo = (_Float16)(v16 - (float)hi);
            const int idx = (b * 400 + oy * 20 + px) * 256 + t;
            ahi[idx] = hi;
            alo[idx] = lo;
        }
    }
}

// ---------------- W2 convert: pc_w[n][ci][tap] -> whi/wlo[n][tap*256+ci] (x16)
__global__ __launch_bounds__(256) void k_wcvt(const float* __restrict__ w2,
        _Float16* __restrict__ whi, _Float16* __restrict__ wlo) {
    const int i = blockIdx.x * 256 + threadIdx.x;  // 5,308,416 outputs
    const int n = i / 20736;
    const int r = i - n * 20736;
    const int tap = r >> 8;
    const int ci = r & 255;
    const float v = w2[(n * 256 + ci) * 81 + tap] * 16.f;
    const _Float16 hi = (_Float16)v;
    whi[i] = hi;
    wlo[i] = (_Float16)(v - (float)hi);
}

// ---------------- p init: p[(b*256+n)*36+pix] = bias[n]  (epilogue atomicAdds)
__global__ __launch_bounds__(256) void k_pinit(const float* __restrict__ bias,
        float* __restrict__ p) {
    const int idx = blockIdx.x * 256 + threadIdx.x;   // 4,718,592
    const int q = idx / 36;                            // b*256+n
    p[idx] = bias[q & 255];
}

// ---------------- conv2 MFMA implicit GEMM v4
// C[m,n] += (1/256) sum_{k in kz slice} A[m,k]*W[n,k]; K = 81*256 tap-major.
// BM=BN=128, BK=32, 4 waves (2x2), wave tile 64x64. Split-K x2: s = 2j+kz,
// 324 steps/block. LDS slot layout: slot = row*4 + phys, phys = logk ^
// ((row>>1)&3)  (hand-verified: 16-lane group covers all 32 banks 2x = free).
// Writes linear (slot=i*256+t); source addr pre-swizzled (rule #21).
__global__ __launch_bounds__(256, 3) void k_conv2m(
        const _Float16* __restrict__ ahi, const _Float16* __restrict__ alo,
        const _Float16* __restrict__ whi, const _Float16* __restrict__ wlo,
        float* __restrict__ p) {
    __shared__ __align__(16) _Float16 lds[16384];  // 32 KB
    _Float16* sAhi = lds;                          // [128 rows][4 slots][8]
    _Float16* sAlo = lds + 4096;
    _Float16* sBhi = lds + 8192;
    _Float16* sBlo = lds + 12288;

    const int t = threadIdx.x;
    const int l = t & 63, w = t >> 6;
    const int lm = l & 15, lk = l >> 4;
    const int m0 = blockIdx.x * 128;
    const int n0 = blockIdx.y * 128;
    const int kz = blockIdx.z;

    // staging: slot = i*256 + t; row = slot>>2, phys = slot&3,
    // logical k-oct = phys ^ ((row>>1)&3); LDS dest linear at slot*8 halfs.
    int abase[2], bbase[2];
#pragma unroll
    for (int i = 0; i < 2; ++i) {
        const int slot = i * 256 + t;
        const int row = slot >> 2, phys = slot & 3;
        const int logk = phys ^ ((row >> 1) & 3);
        const int m = m0 + row;
        const int b = m / 36, pix = m - b * 36;
        const int oy = pix / 6, ox = pix - oy * 6;
        abase[i] = (b * 400 + oy * 40 + ox * 2) * 256 + logk * 8;
        bbase[i] = (n0 + row) * 20736 + logk * 8;
    }

    f32x4 acc[4][4];
#pragma unroll
    for (int mf = 0; mf < 4; ++mf)
#pragma unroll
        for (int nf = 0; nf < 4; ++nf) acc[mf][nf] = (f32x4){0.f, 0.f, 0.f, 0.f};

    const int wm = (w >> 1) * 64, wn = (w & 1) * 64;

    f16x8 rAh[2], rAl[2], rBh[2], rBl[2];

    // step s: tap = s>>3 (ky=tap/9, kx=tap%9), ci0 = (s&7)*32
#define KOFFA(s_) (((((s_) >> 3) / 9) * 20 + (((s_) >> 3) % 9)) * 256 + (((s_) & 7) << 5))
#define LOAD(s_) do { \
        const int ka_ = KOFFA(s_), kb_ = (s_) * 32; \
        rAh[0] = *(const f16x8*)(ahi + abase[0] + ka_); \
        rAl[0] = *(const f16x8*)(alo + abase[0] + ka_); \
        rAh[1] = *(const f16x8*)(ahi + abase[1] + ka_); \
        rAl[1] = *(const f16x8*)(alo + abase[1] + ka_); \
        rBh[0] = *(const f16x8*)(whi + bbase[0] + kb_); \
        rBl[0] = *(const f16x8*)(wlo + bbase[0] + kb_); \
        rBh[1] = *(const f16x8*)(whi + bbase[1] + kb_); \
        rBl[1] = *(const f16x8*)(wlo + bbase[1] + kb_); \
    } while (0)

    LOAD(kz);

    for (int j = 0; j < 324; ++j) {
        __syncthreads();                           // readers done with LDS
        *(f16x8*)(sAhi + t * 8)        = rAh[0];
        *(f16x8*)(sAhi + 2048 + t * 8) = rAh[1];
        *(f16x8*)(sAlo + t * 8)        = rAl[0];
        *(f16x8*)(sAlo + 2048 + t * 8) = rAl[1];
        *(f16x8*)(sBhi + t * 8)        = rBh[0];
        *(f16x8*)(sBhi + 2048 + t * 8) = rBh[1];
        *(f16x8*)(sBlo + t * 8)        = rBl[0];
        *(f16x8*)(sBlo + 2048 + t * 8) = rBl[1];
        __syncthreads();                           // tile visible
        if (j < 323) LOAD(2 * (j + 1) + kz);       // prefetch under MFMA

        f16x8 afh[4], afl[4];
#pragma unroll
        for (int mf = 0; mf < 4; ++mf) {
            const int row = wm + mf * 16 + lm;
            const int off = (row * 4 + (lk ^ ((row >> 1) & 3))) * 8;
            afh[mf] = *(const f16x8*)&sAhi[off];
            afl[mf] = *(const f16x8*)&sAlo[off];
        }
#pragma unroll
        for (int nf = 0; nf < 4; ++nf) {
            const int row = wn + nf * 16 + lm;
            const int off = (row * 4 + (lk ^ ((row >> 1) & 3))) * 8;
            const f16x8 bh = *(const f16x8*)&sBhi[off];
            const f16x8 bl = *(const f16x8*)&sBlo[off];
#pragma unroll
            for (int mf = 0; mf < 4; ++mf) {
                acc[mf][nf] = __builtin_amdgcn_mfma_f32_16x16x32_f16(
                    afh[mf], bh, acc[mf][nf], 0, 0, 0);
                acc[mf][nf] = __builtin_amdgcn_mfma_f32_16x16x32_f16(
                    afh[mf], bl, acc[mf][nf], 0, 0, 0);
                acc[mf][nf] = __builtin_amdgcn_mfma_f32_16x16x32_f16(
                    afl[mf], bh, acc[mf][nf], 0, 0, 0);
            }
        }
    }
#undef LOAD
#undef KOFFA

    // epilogue: D col(n) = lm, row(m) = lk*4 + r; split-K partial accumulate
#pragma unroll
    for (int nf = 0; nf < 4; ++nf) {
        const int n = n0 + wn + nf * 16 + lm;
#pragma unroll
        for (int mf = 0; mf < 4; ++mf) {
#pragma unroll
            for (int r = 0; r < 4; ++r) {
                const int m = m0 + wm + mf * 16 + lk * 4 + r;
                const int b = m / 36, pix = m - b * 36;
                atomicAdd(&p[(b * 256 + n) * 36 + pix],
                          acc[mf][nf][r] * (1.f / 256.f));
            }
        }
    }
}

// ---------------- squash caps in place: [512*1152][8]
__global__ __launch_bounds__(256) void k_squash(float* __restrict__ pc) {
    const long long i = (long long)blockIdx.x * 256 + threadIdx.x;  // 589824
    float* p = pc + i * 8;
    float4 v0 = *(float4*)p;
    float4 v1 = *(float4*)(p + 4);
    const float sq = v0.x * v0.x + v0.y * v0.y + v0.z * v0.z + v0.w * v0.w
                   + v1.x * v1.x + v1.y * v1.y + v1.z * v1.z + v1.w * v1.w;
    const float sc = (sq / (1.f + sq)) / (sqrtf(sq) + 1e-8f);
    v0.x *= sc; v0.y *= sc; v0.z *= sc; v0.w *= sc;
    v1.x *= sc; v1.y *= sc; v1.z *= sc; v1.w *= sc;
    *(float4*)p = v0;
    *(float4*)(p + 4) = v1;
}

// ---------------- fused routing pass v2 (W slice in LDS, 64 b per block):
// u[o] = dot8(W[o,n,d,:], caps[b,n,:]);
// c = 0.1 (uniform) or softmax_o( sum_d u[o]*vsum[b,o,d] );
// sp[b,nc,o,d] = sum_{n in 8-chunk} c[o]*u[o]
// grid (144 nc, 8 bc), block 256: d = t&15, g = t>>4; each thread 4 b.
__global__ __launch_bounds__(256, 2) void k_route(const float* __restrict__ caps,
        const float* __restrict__ W, const float* __restrict__ vsum,
        float* __restrict__ sp, int uniform) {
    __shared__ __align__(16) float Wl[10240];      // [o][n(8)][d(16)][i(8)] 40 KB
    const int nc = blockIdx.x, bc = blockIdx.y;
    const int t = threadIdx.x;
    const int d = t & 15, g = t >> 4;
    const int n0 = nc * 8;

#pragma unroll
    for (int ii = 0; ii < 10; ++ii) {              // 2560 float4 loads, coalesced
        const int idx = (ii * 256 + t) * 4;
        const int o = idx >> 10;
        *(float4*)&Wl[idx] =
            *(const float4*)(W + o * 147456 + n0 * 128 + (idx & 1023));
    }
    __syncthreads();

    float vs[4][10];
    if (!uniform) {
#pragma unroll
        for (int j = 0; j < 4; ++j) {
            const int b = bc * 64 + j * 16 + g;
#pragma unroll
            for (int o = 0; o < 10; ++o)
                vs[j][o] = vsum[b * 160 + o * 16 + d];
        }
    }

    float sacc[4][10];
#pragma unroll
    for (int j = 0; j < 4; ++j)
#pragma unroll
        for (int o = 0; o < 10; ++o) sacc[j][o] = 0.f;

    for (int n = 0; n < 8; ++n) {
        float4 wva[10], wvb[10];                   // W rows held across 4 b
#pragma unroll
        for (int o = 0; o < 10; ++o) {
            const float* wp = &Wl[((o * 8 + n) * 16 + d) * 8];
            wva[o] = *(const float4*)wp;
            wvb[o] = *(const float4*)(wp + 4);
        }
#pragma unroll
        for (int j = 0; j < 4; ++j) {
            const int b = bc * 64 + j * 16 + g;
            const float* cp = caps + ((long long)b * 1152 + n0 + n) * 8;
            const float4 ca = *(const float4*)cp;
            const float4 cb = *(const float4*)(cp + 4);
            float uv[10];
#pragma unroll
            for (int o = 0; o < 10; ++o) {
                float s = wva[o].x * ca.x;
                s = fmaf(wva[o].y, ca.y, s); s = fmaf(wva[o].z, ca.z, s);
                s = fmaf(wva[o].w, ca.w, s);
                s = fmaf(wvb[o].x, cb.x, s); s = fmaf(wvb[o].y, cb.y, s);
                s = fmaf(wvb[o].z, cb.z, s); s = fmaf(wvb[o].w, cb.w, s);
                uv[o] = s;
            }
            float c[10];
            if (uniform) {
#pragma unroll
                for (int o = 0; o < 10; ++o) c[o] = 0.1f;
            } else {
                float dot[10];
#pragma unroll
                for (int o = 0; o < 10; ++o) {
                    float xx = uv[o] * vs[j][o];
                    xx += __shfl_xor(xx, 1);
                    xx += __shfl_xor(xx, 2);
                    xx += __shfl_xor(xx, 4);
                    xx += __shfl_xor(xx, 8);
                    dot[o] = xx;
                }
                float mx = dot[0];
#pragma unroll
                for (int o = 1; o < 10; ++o) mx = fmaxf(mx, dot[o]);
                float sum = 0.f;
#pragma unroll
                for (int o = 0; o < 10; ++o) { c[o] = expf(dot[o] - mx); sum += c[o]; }
                const float inv = 1.f / sum;
#pragma unroll
                for (int o = 0; o < 10; ++o) c[o] *= inv;
            }
#pragma unroll
            for (int o = 0; o < 10; ++o)
                sacc[j][o] = fmaf(c[o], uv[o], sacc[j][o]);
        }
    }
#pragma unroll
    for (int j = 0; j < 4; ++j) {
        const int b = bc * 64 + j * 16 + g;
#pragma unroll
        for (int o = 0; o < 10; ++o)
            sp[((long long)b * 144 + nc) * 160 + o * 16 + d] = sacc[j][o];
    }
}

// ---------------- v = squash(sum_ch sp); vsum = first ? v : vsum + v; vbuf = v
__global__ __launch_bounds__(160) void k_squashv(const float* __restrict__ sp,
        float* __restrict__ vsum, float* __restrict__ vbuf, int first) {
    const int b = blockIdx.x, t = threadIdx.x;     // t = o*16+d
    float s = 0.f;
    for (int ch = 0; ch < 144; ++ch)
        s += sp[((long long)b * 144 + ch) * 160 + t];
    float sq = s * s;
    sq += __shfl_xor(sq, 1);
    sq += __shfl_xor(sq, 2);
    sq += __shfl_xor(sq, 4);
    sq += __shfl_xor(sq, 8);
    const float sc = (sq / (1.f + sq)) / (sqrtf(sq) + 1e-8f);
    const float v = s * sc;
    vbuf[b * 160 + t] = v;
    vsum[b * 160 + t] = first ? v : (vsum[b * 160 + t] + v);
}

// ---------------- logits = ||v||, dec_in = v * onehot(argmax)
__global__ __launch_bounds__(64) void k_logits(const float* __restrict__ v,
        float* __restrict__ logits, float* __restrict__ dec_in) {
    const int b = blockIdx.x * 64 + threadIdx.x;   // 512
    const float* vp = v + (long long)b * 160;
    float nrm[10];
    int amax = 0;
    float best = -1.f;
#pragma unroll
    for (int o = 0; o < 10; ++o) {
        float s = 0.f;
#pragma unroll
        for (int dd = 0; dd < 16; ++dd) { const float xv = vp[o * 16 + dd]; s = fmaf(xv, xv, s); }
        nrm[o] = sqrtf(s);
        if (nrm[o] > best) { best = nrm[o]; amax = o; }  // first max wins
    }
#pragma unroll
    for (int o = 0; o < 10; ++o) logits[b * 10 + o] = nrm[o];
#pragma unroll
    for (int o = 0; o < 10; ++o)
#pragma unroll
        for (int dd = 0; dd < 16; ++dd)
            dec_in[(long long)b * 160 + o * 16 + dd] = (o == amax) ? vp[o * 16 + dd] : 0.f;
}

// ---------------- dense GEMM: C[M,N] = act(A[M,K] @ W[N,K]^T + bias)
template <int ACT>
__global__ __launch_bounds__(256) void k_gemm(const float* __restrict__ A,
        const float* __restrict__ W, const float* __restrict__ bias,
        float* __restrict__ C, int N, int K) {
    __shared__ float As[16][68];
    __shared__ float Bs[16][68];
    const int m0 = blockIdx.x * 64, n0 = blockIdx.y * 64;
    const int t = threadIdx.x;
    const int kl = t & 15, rr = t >> 4;
    const int tm = t & 15, tn = t >> 4;

    float acc[4][4];
#pragma unroll
    for (int i = 0; i < 4; ++i)
#pragma unroll
        for (int j = 0; j < 4; ++j) acc[i][j] = 0.f;

    for (int k0 = 0; k0 < K; k0 += 16) {
#pragma unroll
        for (int i = 0; i < 4; ++i) {
            As[kl][rr + i * 16] = A[(m0 + rr + i * 16) * K + k0 + kl];
            const int n = n0 + rr + i * 16;
            Bs[kl][rr + i * 16] = (n < N) ? W[(long long)n * K + k0 + kl] : 0.f;
        }
        __syncthreads();
#pragma unroll
        for (int kk = 0; kk < 16; ++kk) {
            float a[4], bb[4];
#pragma unroll
            for (int i = 0; i < 4; ++i) a[i] = As[kk][tm * 4 + i];
#pragma unroll
            for (int j = 0; j < 4; ++j) bb[j] = Bs[kk][tn * 4 + j];
#pragma unroll
            for (int i = 0; i < 4; ++i)
#pragma unroll
                for (int j = 0; j < 4; ++j)
                    acc[i][j] = fmaf(a[i], bb[j], acc[i][j]);
        }
        __syncthreads();
    }
#pragma unroll
    for (int j = 0; j < 4; ++j) {
        const int n = n0 + tn * 4 + j;
        if (n < N) {
            const float bv = bias[n];
#pragma unroll
            for (int i = 0; i < 4; ++i) {
                const int m = m0 + tm * 4 + i;
                float xv = acc[i][j] + bv;
                if (ACT == 0) xv = fmaxf(xv, 0.f);
                else          xv = 1.f / (1.f + expf(-xv));
                C[(long long)m * N + n] = xv;
            }
        }
    }
}

// ============================================================================
extern "C" void kernel_launch(void* const* d_in, const int* in_sizes, int n_in,
                              void* d_out, int out_size, void* d_ws, size_t ws_size,
                              hipStream_t stream) {
    const float* x      = (const float*)d_in[0];
    const float* conv_w = (const float*)d_in[1];
    const float* conv_b = (const float*)d_in[2];
    const float* pc_w   = (const float*)d_in[3];
    const float* pc_b   = (const float*)d_in[4];
    const float* Wrt    = (const float*)d_in[5];
    const float* dw1    = (const float*)d_in[6];
    const float* db1    = (const float*)d_in[7];
    const float* dw2    = (const float*)d_in[8];
    const float* db2    = (const float*)d_in[9];
    const float* dw3    = (const float*)d_in[10];
    const float* db3    = (const float*)d_in[11];

    float* out = (float*)d_out;                 // [0,5120) logits, then recon
    char* wsb  = (char*)d_ws;

    _Float16* ahi = (_Float16*)(wsb);                 // 104,857,600 B
    _Float16* alo = (_Float16*)(wsb + 104857600);
    _Float16* whi = (_Float16*)(wsb + 209715200);     // 10,616,832 B
    _Float16* wlo = (_Float16*)(wsb + 220332032);
    float* caps = (float*)(wsb + 230948864);          // 18,874,368 B
    // staging region dead after conv2m -> alias at offset 0
    float* spart= (float*)(wsb);                      // 47,185,920 B
    float* vsum = (float*)(wsb + 47185920);
    float* vbuf = (float*)(wsb + 47513600);
    float* din  = (float*)(wsb + 47841280);
    float* h1   = (float*)(wsb + 48168960);
    float* h2   = (float*)(wsb + 49217536);
    // total ws use: 249,823,232 bytes

    k_conv1<<<dim3(512, 5), 256, 0, stream>>>(x, conv_w, conv_b, ahi, alo);
    k_wcvt<<<20736, 256, 0, stream>>>(pc_w, whi, wlo);
    k_pinit<<<18432, 256, 0, stream>>>(pc_b, caps);
    k_conv2m<<<dim3(144, 2, 2), 256, 0, stream>>>(ahi, alo, whi, wlo, caps);
    k_squash<<<2304, 256, 0, stream>>>(caps);

    // routing via vsum linearity: b_logit after iter k == u . (v0+..+v_{k-1})
    k_route<<<dim3(144, 8), 256, 0, stream>>>(caps, Wrt, vsum, spart, 1);
    k_squashv<<<512, 160, 0, stream>>>(spart, vsum, vbuf, 1);   // vsum = v0
    k_route<<<dim3(144, 8), 256, 0, stream>>>(caps, Wrt, vsum, spart, 0);
    k_squashv<<<512, 160, 0, stream>>>(spart, vsum, vbuf, 0);   // vsum = v0+v1
    k_route<<<dim3(144, 8), 256, 0, stream>>>(caps, Wrt, vsum, spart, 0);
    k_squashv<<<512, 160, 0, stream>>>(spart, vsum, vbuf, 0);   // vbuf = v2

    k_logits<<<8, 64, 0, stream>>>(vbuf, out, din);

    k_gemm<0><<<dim3(8, 8),  256, 0, stream>>>(din, dw1, db1, h1, 512, 160);
    k_gemm<0><<<dim3(8, 16), 256, 0, stream>>>(h1,  dw2, db2, h2, 1024, 512);
    k_gemm<1><<<dim3(8, 13), 256, 0, stream>>>(h2,  dw3, db3, out + 5120, 784, 1024);
}